// Round 5
// baseline (236.970 us; speedup 1.0000x reference)
//
#include <hip/hip_runtime.h>
#include <cstdint>

// BinarizedLeNet5 / CIFAR10, B=2048.  Round 5: best-of-each consolidation.
//  k0   : pack fc1/fc2 i8 B-fragments, conv2 popc words, signed conv1 w, bn params.
//  k13  : conv1 fp32 (2 channels/body -> 8 FMA chains, verbatim per-channel order)
//         + pool + bn1 -> packed word in LDS tile -> conv2 popc (round-2 proven)
//         + pool + bn2 -> +-1 BYTES to fc1A (feeds i8 MFMA fc1).
//  k4   : fc1 i8 GEMM [2048,4096]x[4096,512] + bn3 -> +-1 bytes (round-4 proven).
//  k56  : fc2 i8 GEMM (16-sample tiles) + bn4 + clip + fc3 + log_softmax (fused).
// All binary-layer sums exact integers; float epilogues verbatim from absmax-0.0
// kernels. 4 launches (was 5) to cut serialized-launch gaps.

#define BSZ 2048

typedef int vi4 __attribute__((ext_vector_type(4)));

__device__ __forceinline__ float sgnf(float w) {
    return (w > 0.f) ? 1.f : ((w < 0.f) ? -1.f : 0.f);
}
__device__ __forceinline__ uint32_t sgnb4(float a, float b, float c, float d) {
    return (a > 0.f ? 1u : 0xFFu) | ((b > 0.f ? 1u : 0xFFu) << 8) |
           ((c > 0.f ? 1u : 0xFFu) << 16) | ((d > 0.f ? 1u : 0xFFu) << 24);
}

// ---------------- k0: all packing ----------------
// grid: [0,512) fc1 frags | [512,544) fc2 frags | 544 wp2+bnp2 | 545 sw1+bnp1
//       | 546 bnp3+bnp4
__global__ __launch_bounds__(256) void k0_pack(
    const float* __restrict__ c1w, const float* __restrict__ c2w,
    const float* __restrict__ f1w, const float* __restrict__ f2w,
    const float* __restrict__ c1b, const float* __restrict__ c2b,
    const float* __restrict__ f1b, const float* __restrict__ f2b,
    const float* __restrict__ b1g, const float* __restrict__ b1b,
    const float* __restrict__ b1m, const float* __restrict__ b1v,
    const float* __restrict__ b2g, const float* __restrict__ b2b,
    const float* __restrict__ b2m, const float* __restrict__ b2v,
    const float* __restrict__ b3g, const float* __restrict__ b3b,
    const float* __restrict__ b3m, const float* __restrict__ b3v,
    const float* __restrict__ b4g, const float* __restrict__ b4b,
    const float* __restrict__ b4m, const float* __restrict__ b4v,
    float* __restrict__ sw1, uint32_t* __restrict__ wp2,
    uint32_t* __restrict__ wfF1, uint32_t* __restrict__ wfF2,
    float* __restrict__ bnp1, float* __restrict__ bnp2,
    float* __restrict__ bnp3, float* __restrict__ bnp4) {
    int bid = blockIdx.x, t = threadIdx.x;
    if (bid < 512) {
        // fc1 i8 B-frags: e = (nt*64 + s)*64 + l ; o = nt*16+(l&15),
        // k = s*64 + (l>>4)*16 + j
        int e = bid * 256 + t;
        int l = e & 63, s = (e >> 6) & 63, nt = e >> 12;
        int o = nt * 16 + (l & 15);
        int f0 = s * 64 + (l >> 4) * 16;
        const float4* p4 = (const float4*)(f1w + (size_t)o * 4096 + f0);
        float4 w0 = p4[0], w1 = p4[1], w2 = p4[2], w3 = p4[3];
        uint4 r;
        r.x = sgnb4(w0.x, w0.y, w0.z, w0.w);
        r.y = sgnb4(w1.x, w1.y, w1.z, w1.w);
        r.z = sgnb4(w2.x, w2.y, w2.z, w2.w);
        r.w = sgnb4(w3.x, w3.y, w3.z, w3.w);
        ((uint4*)wfF1)[e] = r;
    } else if (bid < 544) {
        // fc2 i8 B-frags: e = (nt*8 + s)*64 + l
        int e = (bid - 512) * 256 + t;
        int l = e & 63, s = (e >> 6) & 7, nt = e >> 9;
        int o = nt * 16 + (l & 15);
        int f0 = s * 64 + (l >> 4) * 16;
        const float4* p4 = (const float4*)(f2w + (size_t)o * 512 + f0);
        float4 w0 = p4[0], w1 = p4[1], w2 = p4[2], w3 = p4[3];
        uint4 r;
        r.x = sgnb4(w0.x, w0.y, w0.z, w0.w);
        r.y = sgnb4(w1.x, w1.y, w1.z, w1.w);
        r.z = sgnb4(w2.x, w2.y, w2.z, w2.w);
        r.w = sgnb4(w3.x, w3.y, w3.z, w3.w);
        ((uint4*)wfF2)[e] = r;
    } else if (bid == 544) {
        // conv2 popc words wp2[o*16+k], k<9; + bn2 params
        for (int i = t; i < 1024; i += 256) {
            int o = i >> 4, k = i & 15;
            uint32_t word = 0;
            if (k < 9)
                for (int c = 0; c < 32; c++)
                    if (c2w[(o * 32 + c) * 9 + k] > 0.f) word |= (1u << c);
            wp2[i] = word;
        }
        if (t < 64) {
            float inv = __fdiv_rn(b2g[t], __fsqrt_rn(b2v[t] + 1e-5f));
            float add = __fsub_rn(b2b[t], __fmul_rn(b2m[t], inv));
            bnp2[t * 4] = inv; bnp2[t * 4 + 1] = add;
            bnp2[t * 4 + 2] = c2b[t]; bnp2[t * 4 + 3] = 0.f;
        }
    } else if (bid == 545) {
        for (int i = t; i < 1024; i += 256) {
            int o = i >> 5, r = i & 31;
            sw1[i] = (r < 27) ? sgnf(c1w[o * 27 + r]) : 0.f;
        }
        if (t < 32) {
            float inv = __fdiv_rn(b1g[t], __fsqrt_rn(b1v[t] + 1e-5f));
            float add = __fsub_rn(b1b[t], __fmul_rn(b1m[t], inv));
            bnp1[t * 4] = inv; bnp1[t * 4 + 1] = add;
            bnp1[t * 4 + 2] = c1b[t]; bnp1[t * 4 + 3] = 0.f;
        }
    } else {
        for (int i = t; i < 512; i += 256) {
            float inv = __fdiv_rn(b3g[i], __fsqrt_rn(b3v[i] + 1e-5f));
            float add = __fsub_rn(b3b[i], __fmul_rn(b3m[i], inv));
            bnp3[i * 4] = inv; bnp3[i * 4 + 1] = add;
            bnp3[i * 4 + 2] = f1b[i]; bnp3[i * 4 + 3] = 0.f;
        }
        if (t < 256) {
            float inv = __fdiv_rn(b4g[t], __fsqrt_rn(b4v[t] + 1e-5f));
            float add = __fsub_rn(b4b[t], __fmul_rn(b4m[t], inv));
            bnp4[t * 4] = inv; bnp4[t * 4 + 1] = add;
            bnp4[t * 4 + 2] = f2b[t]; bnp4[t * 4 + 3] = 0.f;
        }
    }
}

// ---------------- k13: conv1 fp32 + conv2 popc, one block/sample ----------------
__global__ __launch_bounds__(256) void k13_conv12(
    const float* __restrict__ x, const float* __restrict__ sw,
    const float* __restrict__ bnp1, const uint32_t* __restrict__ wp2,
    const float* __restrict__ bnp2, uint8_t* __restrict__ fc1A) {
    const int P = 19;
    __shared__ uint32_t tile[18 * 19];
    int b = blockIdx.x, t = threadIdx.x;
    for (int i = t; i < 18 * 19; i += 256) tile[i] = 0;

    // ---- phase 1: conv1 + pool + bn1 -> packed word ----
    int py = t >> 4, px = t & 15;
    {
        int y0 = 2 * py - 1, x0 = 2 * px - 1;
        float in[48];
#pragma unroll
        for (int c = 0; c < 3; c++) {
            const float* xc = x + ((size_t)b * 3 + c) * 1024;
#pragma unroll
            for (int i = 0; i < 4; i++) {
                int yy = y0 + i;
                bool ry = (unsigned)yy < 32u;
#pragma unroll
                for (int j = 0; j < 4; j++) {
                    int xx = x0 + j;
                    in[c * 16 + i * 4 + j] =
                        (ry && (unsigned)xx < 32u) ? xc[yy * 32 + xx] : 0.f;
                }
            }
        }
        uint32_t word = 0;
        // 2 channels per body: 216 fmacs per s_load wait, 8 indep chains.
        // Per-channel fmaf chain order identical to the round-2 passing kernel.
#pragma unroll 2
        for (int o2 = 0; o2 < 16; o2++) {
            int oA = 2 * o2, oB = oA + 1;
            const float* wA = sw + oA * 32;          // uniform -> s_load
            const float* wB = sw + oB * 32;
            float a00 = 0.f, a01 = 0.f, a10 = 0.f, a11 = 0.f;
            float c00 = 0.f, c01 = 0.f, c10 = 0.f, c11 = 0.f;
#pragma unroll
            for (int c = 0; c < 3; c++)
#pragma unroll
                for (int ky = 0; ky < 3; ky++)
#pragma unroll
                    for (int kx = 0; kx < 3; kx++) {
                        int ti = c * 9 + ky * 3 + kx;
                        float i00 = in[c * 16 + ky * 4 + kx];
                        float i01 = in[c * 16 + ky * 4 + kx + 1];
                        float i10 = in[c * 16 + (ky + 1) * 4 + kx];
                        float i11 = in[c * 16 + (ky + 1) * 4 + kx + 1];
                        float wvA = wA[ti], wvB = wB[ti];
                        a00 = fmaf(i00, wvA, a00); a01 = fmaf(i01, wvA, a01);
                        a10 = fmaf(i10, wvA, a10); a11 = fmaf(i11, wvA, a11);
                        c00 = fmaf(i00, wvB, c00); c01 = fmaf(i01, wvB, c01);
                        c10 = fmaf(i10, wvB, c10); c11 = fmaf(i11, wvB, c11);
                    }
            float4 pA = ((const float4*)bnp1)[oA];
            float mxA = fmaxf(fmaxf(a00, a01), fmaxf(a10, a11));
            float hA = __fadd_rn(mxA, pA.z);
            float vA = __fadd_rn(__fmul_rn(hA, pA.x), pA.y);
            word |= (vA > 0.f) ? (1u << oA) : 0u;
            float4 pB = ((const float4*)bnp1)[oB];
            float mxB = fmaxf(fmaxf(c00, c01), fmaxf(c10, c11));
            float hB = __fadd_rn(mxB, pB.z);
            float vB = __fadd_rn(__fmul_rn(hB, pB.x), pB.y);
            word |= (vB > 0.f) ? (1u << oB) : 0u;
        }
        __syncthreads();                             // pad zero-fill done
        tile[(py + 1) * P + px + 1] = word;
    }
    __syncthreads();

    // ---- phase 2: conv2 popc + pool + bn2 -> +-1 bytes (round-3 proven) ----
    {
        int wv = t >> 6, l = t & 63;
        int qy = l >> 3, qx = l & 7;
        uint32_t val[16];
#pragma unroll
        for (int i = 0; i < 4; i++)
#pragma unroll
            for (int j = 0; j < 4; j++)
                val[i * 4 + j] = tile[(2 * qy + i) * P + 2 * qx + j];
        bool top = (qy == 0), bot = (qy == 7), lef = (qx == 0), rig = (qx == 7);
        bool ctl = top && lef, ctr = top && rig, cbl = bot && lef, cbr = bot && rig;
#pragma unroll 2
        for (int oi = 0; oi < 16; oi++) {
            int o = wv * 16 + oi;
            const uint32_t* wo = wp2 + o * 16;       // uniform -> s_load
            uint32_t w0 = wo[0], w1 = wo[1], w2 = wo[2], w3 = wo[3], w4 = wo[4],
                     w5 = wo[5], w6 = wo[6], w7 = wo[7], w8 = wo[8];
            int t0 = 32 - 2 * __popc(w0), t1 = 32 - 2 * __popc(w1),
                t2 = 32 - 2 * __popc(w2), t3 = 32 - 2 * __popc(w3),
                t5 = 32 - 2 * __popc(w5), t6 = 32 - 2 * __popc(w6),
                t7 = 32 - 2 * __popc(w7), t8 = 32 - 2 * __popc(w8);
            int R0 = t0 + t1 + t2, R2 = t6 + t7 + t8;
            int C0 = t0 + t3 + t6, C2 = t2 + t5 + t8;
            int P00 = __popc(val[0] ^ w0) + __popc(val[1] ^ w1) + __popc(val[2] ^ w2) +
                      __popc(val[4] ^ w3) + __popc(val[5] ^ w4) + __popc(val[6] ^ w5) +
                      __popc(val[8] ^ w6) + __popc(val[9] ^ w7) + __popc(val[10] ^ w8);
            int P01 = __popc(val[1] ^ w0) + __popc(val[2] ^ w1) + __popc(val[3] ^ w2) +
                      __popc(val[5] ^ w3) + __popc(val[6] ^ w4) + __popc(val[7] ^ w5) +
                      __popc(val[9] ^ w6) + __popc(val[10] ^ w7) + __popc(val[11] ^ w8);
            int P10 = __popc(val[4] ^ w0) + __popc(val[5] ^ w1) + __popc(val[6] ^ w2) +
                      __popc(val[8] ^ w3) + __popc(val[9] ^ w4) + __popc(val[10] ^ w5) +
                      __popc(val[12] ^ w6) + __popc(val[13] ^ w7) + __popc(val[14] ^ w8);
            int P11 = __popc(val[5] ^ w0) + __popc(val[6] ^ w1) + __popc(val[7] ^ w2) +
                      __popc(val[9] ^ w3) + __popc(val[10] ^ w4) + __popc(val[11] ^ w5) +
                      __popc(val[13] ^ w6) + __popc(val[14] ^ w7) + __popc(val[15] ^ w8);
            int s00 = 288 - 2 * P00 - ((top ? R0 : 0) + (lef ? C0 : 0) - (ctl ? t0 : 0));
            int s01 = 288 - 2 * P01 - ((top ? R0 : 0) + (rig ? C2 : 0) - (ctr ? t2 : 0));
            int s10 = 288 - 2 * P10 - ((bot ? R2 : 0) + (lef ? C0 : 0) - (cbl ? t6 : 0));
            int s11 = 288 - 2 * P11 - ((bot ? R2 : 0) + (rig ? C2 : 0) - (cbr ? t8 : 0));
            int mi = max(max(s00, s01), max(s10, s11));
            float4 p = ((const float4*)bnp2)[o];     // uniform -> s_load
            float h = __fadd_rn((float)mi, p.z);
            float bv = __fadd_rn(__fmul_rn(h, p.x), p.y);
            // +-1 byte in NCHW flatten order: f = o*64 + qy*8 + qx = o*64 + l
            fc1A[(size_t)b * 4096 + o * 64 + l] = (uint8_t)(bv > 0.f ? 1 : 0xFF);
        }
    }
}

// ---------------- k4: fc1 i8 GEMM [2048,4096]x[4096,512] + bn3 ----------------
__global__ __launch_bounds__(256) void k4_fc1(
    const uint8_t* __restrict__ fc1A, const uint32_t* __restrict__ wfF1,
    const float* __restrict__ bnp3, uint8_t* __restrict__ fc2A) {
    __shared__ __align__(16) uint8_t Ab[64 * 528];
    int t = threadIdx.x;
    int mb = blockIdx.x >> 3, nb = blockIdx.x & 7;
    int l = t & 63, w = t >> 6;
    int mlane = l & 15, kq = l >> 4;
    int o = nb * 64 + w * 16 + mlane;
    int nt = nb * 4 + w;
    const vi4* wf = (const vi4*)wfF1;
    vi4 acc[4];
#pragma unroll
    for (int i = 0; i < 4; i++) acc[i] = (vi4){0, 0, 0, 0};
    int row = t >> 2, seg = t & 3;
    const uint8_t* arow = fc1A + (size_t)(mb * 64 + row) * 4096 + seg * 128;
    for (int ch = 0; ch < 8; ch++) {
        if (ch) __syncthreads();
        const uint4* src = (const uint4*)(arow + ch * 512);
        uint4* dst = (uint4*)(Ab + row * 528 + seg * 128);
#pragma unroll
        for (int i = 0; i < 8; i++) dst[i] = src[i];
        __syncthreads();
#pragma unroll
        for (int s8 = 0; s8 < 8; s8++) {
            vi4 bfr = wf[(nt * 64 + ch * 8 + s8) * 64 + l];
#pragma unroll
            for (int ms = 0; ms < 4; ms++) {
                vi4 a = *(const vi4*)(Ab + (ms * 16 + mlane) * 528 +
                                      s8 * 64 + kq * 16);
                acc[ms] = __builtin_amdgcn_mfma_i32_16x16x64_i8(a, bfr, acc[ms], 0, 0, 0);
            }
        }
    }
    float4 p = ((const float4*)bnp3)[o];
#pragma unroll
    for (int ms = 0; ms < 4; ms++)
#pragma unroll
        for (int r = 0; r < 4; r++) {
            int m = mb * 64 + ms * 16 + kq * 4 + r;
            float h = __fadd_rn((float)acc[ms][r], p.z);
            float bv = __fadd_rn(__fmul_rn(h, p.x), p.y);
            fc2A[(size_t)m * 512 + o] = (uint8_t)(bv > 0.f ? 1 : 0xFF);
        }
}

// ---------------- k56: fc2 i8 GEMM + bn4 + clip + fc3 + log_softmax ----------
// block = 16 samples; wave w covers 64 of 256 outputs; then fc3 from LDS.
__global__ __launch_bounds__(256) void k56_fc23(
    const uint8_t* __restrict__ fc2A, const uint32_t* __restrict__ wfF2,
    const float* __restrict__ bnp4, const float* __restrict__ f3w,
    const float* __restrict__ f3b, float* __restrict__ out) {
    __shared__ __align__(16) uint8_t Ab[16 * 528];
    __shared__ float hbuf[16 * 256];
    int t = threadIdx.x;
    int m0 = blockIdx.x * 16;
    int l = t & 63, w = t >> 6;
    int ml = l & 15, kq = l >> 4;
    {
        int row = t >> 4, seg = t & 15;
        const uint4* src = (const uint4*)(fc2A + (size_t)(m0 + row) * 512 + seg * 32);
        uint4* dst = (uint4*)(Ab + row * 528 + seg * 32);
        dst[0] = src[0]; dst[1] = src[1];
    }
    __syncthreads();
    const vi4* wf = (const vi4*)wfF2;
    vi4 acc[4];
#pragma unroll
    for (int i = 0; i < 4; i++) acc[i] = (vi4){0, 0, 0, 0};
#pragma unroll
    for (int s = 0; s < 8; s++) {
        vi4 a = *(const vi4*)(Ab + ml * 528 + s * 64 + kq * 16);
#pragma unroll
        for (int j = 0; j < 4; j++) {
            int nt = w * 4 + j;
            vi4 bfr = wf[(nt * 8 + s) * 64 + l];
            acc[j] = __builtin_amdgcn_mfma_i32_16x16x64_i8(a, bfr, acc[j], 0, 0, 0);
        }
    }
#pragma unroll
    for (int j = 0; j < 4; j++) {
        int o = (w * 4 + j) * 16 + ml;
        float4 p = ((const float4*)bnp4)[o];
#pragma unroll
        for (int r = 0; r < 4; r++) {
            int m = kq * 4 + r;
            float h = __fadd_rn((float)acc[j][r], p.z);
            float bv = __fadd_rn(__fmul_rn(h, p.x), p.y);
            bv = fminf(1.f, fmaxf(-1.f, bv));
            hbuf[m * 256 + o] = bv;
        }
    }
    __syncthreads();
    // fc3 + log_softmax: wave w -> samples w*4 .. w*4+3 (verbatim round-1 math)
    for (int q = 0; q < 4; q++) {
        int sm = w * 4 + q;
        float4 hv = ((const float4*)(hbuf + sm * 256))[l];
        float logits[10];
#pragma unroll
        for (int jj = 0; jj < 10; jj++) {
            float4 w4 = ((const float4*)(f3w + jj * 256))[l];
            float pp = hv.x * w4.x + hv.y * w4.y + hv.z * w4.z + hv.w * w4.w;
#pragma unroll
            for (int off = 32; off > 0; off >>= 1) pp += __shfl_xor(pp, off, 64);
            logits[jj] = pp + f3b[jj];
        }
        float mx = logits[0];
#pragma unroll
        for (int jj = 1; jj < 10; jj++) mx = fmaxf(mx, logits[jj]);
        float sum = 0.f;
#pragma unroll
        for (int jj = 0; jj < 10; jj++) sum += expf(logits[jj] - mx);
        float ls = mx + logf(sum);
        if (l < 10) out[(size_t)(m0 + sm) * 10 + l] = logits[l] - ls;
    }
}

extern "C" void kernel_launch(void* const* d_in, const int* in_sizes, int n_in,
                              void* d_out, int out_size, void* d_ws, size_t ws_size,
                              hipStream_t stream) {
    (void)in_sizes; (void)n_in; (void)out_size; (void)ws_size;
    const float* x   = (const float*)d_in[0];
    const float* c1w = (const float*)d_in[1];
    const float* c1b = (const float*)d_in[2];
    const float* b1g = (const float*)d_in[3];
    const float* b1b = (const float*)d_in[4];
    const float* b1m = (const float*)d_in[5];
    const float* b1v = (const float*)d_in[6];
    const float* c2w = (const float*)d_in[7];
    const float* c2b = (const float*)d_in[8];
    const float* b2g = (const float*)d_in[9];
    const float* b2b = (const float*)d_in[10];
    const float* b2m = (const float*)d_in[11];
    const float* b2v = (const float*)d_in[12];
    const float* f1w = (const float*)d_in[13];
    const float* f1b = (const float*)d_in[14];
    const float* b3g = (const float*)d_in[15];
    const float* b3b = (const float*)d_in[16];
    const float* b3m = (const float*)d_in[17];
    const float* b3v = (const float*)d_in[18];
    const float* f2w = (const float*)d_in[19];
    const float* f2b = (const float*)d_in[20];
    const float* b4g = (const float*)d_in[21];
    const float* b4b = (const float*)d_in[22];
    const float* b4m = (const float*)d_in[23];
    const float* b4v = (const float*)d_in[24];
    const float* f3w = (const float*)d_in[25];
    const float* f3b = (const float*)d_in[26];
    float* out = (float*)d_out;

    uint8_t* ws = (uint8_t*)d_ws;
    uint8_t*  fc1A = ws + 0;                        // [2048,4096] i8   8 MB
    uint8_t*  fc2A = ws + 8388608;                  // [2048,512]  i8   1 MB
    float*    sw1  = (float*)   (ws + 9437184);     // [32,32]
    float*    bnp1 = (float*)   (ws + 9441280);
    float*    bnp2 = (float*)   (ws + 9441792);
    float*    bnp3 = (float*)   (ws + 9442816);
    float*    bnp4 = (float*)   (ws + 9451008);
    uint32_t* wp2  = (uint32_t*)(ws + 9455104);     // [64,16] popc words
    uint32_t* wfF2 = (uint32_t*)(ws + 9459200);     // 128 KB
    uint32_t* wfF1 = (uint32_t*)(ws + 9590272);     // 2 MB

    k0_pack<<<547, 256, 0, stream>>>(c1w, c2w, f1w, f2w, c1b, c2b, f1b, f2b,
                                     b1g, b1b, b1m, b1v, b2g, b2b, b2m, b2v,
                                     b3g, b3b, b3m, b3v, b4g, b4b, b4m, b4v,
                                     sw1, wp2, wfF1, wfF2, bnp1, bnp2, bnp3, bnp4);
    k13_conv12<<<BSZ, 256, 0, stream>>>(x, sw1, bnp1, wp2, bnp2, fc1A);
    k4_fc1<<<256, 256, 0, stream>>>(fc1A, wfF1, bnp3, fc2A);
    k56_fc23<<<128, 256, 0, stream>>>(fc2A, wfF2, bnp4, f3w, f3b, out);
}

// Round 6
// 234.802 us; speedup vs baseline: 1.0092x; 1.0092x over previous
//
#include <hip/hip_runtime.h>
#include <cstdint>

// BinarizedLeNet5 / CIFAR10, B=2048.  Round 6: R5 structure, conv1 reverted to
// the round-2 verbatim single-channel loop (measured 53 us standalone).
//  k0   : pack fc1/fc2 i8 B-fragments, conv2 popc words, signed conv1 w, bn params.
//  k13  : conv1 fp32 (R2-verbatim) + pool + bn1 -> word tile -> conv2 popc
//         (R3-proven) + pool + bn2 -> +-1 bytes for i8 fc1.
//  k4   : fc1 i8 GEMM [2048,4096]x[4096,512] + bn3 -> +-1 bytes (R4-proven).
//  k56  : fc2 i8 GEMM (16-sample tiles) + bn4 + clip + fc3 + log_softmax (R5-proven).
// All binary sums exact integers; float epilogues verbatim from absmax-0.0 kernels.

#define BSZ 2048

typedef int vi4 __attribute__((ext_vector_type(4)));

__device__ __forceinline__ float sgnf(float w) {
    return (w > 0.f) ? 1.f : ((w < 0.f) ? -1.f : 0.f);
}
__device__ __forceinline__ uint32_t sgnb4(float a, float b, float c, float d) {
    return (a > 0.f ? 1u : 0xFFu) | ((b > 0.f ? 1u : 0xFFu) << 8) |
           ((c > 0.f ? 1u : 0xFFu) << 16) | ((d > 0.f ? 1u : 0xFFu) << 24);
}

// ---------------- k0: all packing ----------------
// grid: [0,512) fc1 frags | [512,544) fc2 frags | 544 wp2+bnp2 | 545 sw1+bnp1
//       | 546 bnp3+bnp4
__global__ __launch_bounds__(256) void k0_pack(
    const float* __restrict__ c1w, const float* __restrict__ c2w,
    const float* __restrict__ f1w, const float* __restrict__ f2w,
    const float* __restrict__ c1b, const float* __restrict__ c2b,
    const float* __restrict__ f1b, const float* __restrict__ f2b,
    const float* __restrict__ b1g, const float* __restrict__ b1b,
    const float* __restrict__ b1m, const float* __restrict__ b1v,
    const float* __restrict__ b2g, const float* __restrict__ b2b,
    const float* __restrict__ b2m, const float* __restrict__ b2v,
    const float* __restrict__ b3g, const float* __restrict__ b3b,
    const float* __restrict__ b3m, const float* __restrict__ b3v,
    const float* __restrict__ b4g, const float* __restrict__ b4b,
    const float* __restrict__ b4m, const float* __restrict__ b4v,
    float* __restrict__ sw1, uint32_t* __restrict__ wp2,
    uint32_t* __restrict__ wfF1, uint32_t* __restrict__ wfF2,
    float* __restrict__ bnp1, float* __restrict__ bnp2,
    float* __restrict__ bnp3, float* __restrict__ bnp4) {
    int bid = blockIdx.x, t = threadIdx.x;
    if (bid < 512) {
        // fc1 i8 B-frags: e = (nt*64 + s)*64 + l ; o = nt*16+(l&15),
        // k = s*64 + (l>>4)*16 + j
        int e = bid * 256 + t;
        int l = e & 63, s = (e >> 6) & 63, nt = e >> 12;
        int o = nt * 16 + (l & 15);
        int f0 = s * 64 + (l >> 4) * 16;
        const float4* p4 = (const float4*)(f1w + (size_t)o * 4096 + f0);
        float4 w0 = p4[0], w1 = p4[1], w2 = p4[2], w3 = p4[3];
        uint4 r;
        r.x = sgnb4(w0.x, w0.y, w0.z, w0.w);
        r.y = sgnb4(w1.x, w1.y, w1.z, w1.w);
        r.z = sgnb4(w2.x, w2.y, w2.z, w2.w);
        r.w = sgnb4(w3.x, w3.y, w3.z, w3.w);
        ((uint4*)wfF1)[e] = r;
    } else if (bid < 544) {
        // fc2 i8 B-frags: e = (nt*8 + s)*64 + l
        int e = (bid - 512) * 256 + t;
        int l = e & 63, s = (e >> 6) & 7, nt = e >> 9;
        int o = nt * 16 + (l & 15);
        int f0 = s * 64 + (l >> 4) * 16;
        const float4* p4 = (const float4*)(f2w + (size_t)o * 512 + f0);
        float4 w0 = p4[0], w1 = p4[1], w2 = p4[2], w3 = p4[3];
        uint4 r;
        r.x = sgnb4(w0.x, w0.y, w0.z, w0.w);
        r.y = sgnb4(w1.x, w1.y, w1.z, w1.w);
        r.z = sgnb4(w2.x, w2.y, w2.z, w2.w);
        r.w = sgnb4(w3.x, w3.y, w3.z, w3.w);
        ((uint4*)wfF2)[e] = r;
    } else if (bid == 544) {
        // conv2 popc words wp2[o*16+k], k<9; + bn2 params
        for (int i = t; i < 1024; i += 256) {
            int o = i >> 4, k = i & 15;
            uint32_t word = 0;
            if (k < 9)
                for (int c = 0; c < 32; c++)
                    if (c2w[(o * 32 + c) * 9 + k] > 0.f) word |= (1u << c);
            wp2[i] = word;
        }
        if (t < 64) {
            float inv = __fdiv_rn(b2g[t], __fsqrt_rn(b2v[t] + 1e-5f));
            float add = __fsub_rn(b2b[t], __fmul_rn(b2m[t], inv));
            bnp2[t * 4] = inv; bnp2[t * 4 + 1] = add;
            bnp2[t * 4 + 2] = c2b[t]; bnp2[t * 4 + 3] = 0.f;
        }
    } else if (bid == 545) {
        for (int i = t; i < 1024; i += 256) {
            int o = i >> 5, r = i & 31;
            sw1[i] = (r < 27) ? sgnf(c1w[o * 27 + r]) : 0.f;
        }
        if (t < 32) {
            float inv = __fdiv_rn(b1g[t], __fsqrt_rn(b1v[t] + 1e-5f));
            float add = __fsub_rn(b1b[t], __fmul_rn(b1m[t], inv));
            bnp1[t * 4] = inv; bnp1[t * 4 + 1] = add;
            bnp1[t * 4 + 2] = c1b[t]; bnp1[t * 4 + 3] = 0.f;
        }
    } else {
        for (int i = t; i < 512; i += 256) {
            float inv = __fdiv_rn(b3g[i], __fsqrt_rn(b3v[i] + 1e-5f));
            float add = __fsub_rn(b3b[i], __fmul_rn(b3m[i], inv));
            bnp3[i * 4] = inv; bnp3[i * 4 + 1] = add;
            bnp3[i * 4 + 2] = f1b[i]; bnp3[i * 4 + 3] = 0.f;
        }
        if (t < 256) {
            float inv = __fdiv_rn(b4g[t], __fsqrt_rn(b4v[t] + 1e-5f));
            float add = __fsub_rn(b4b[t], __fmul_rn(b4m[t], inv));
            bnp4[t * 4] = inv; bnp4[t * 4 + 1] = add;
            bnp4[t * 4 + 2] = f2b[t]; bnp4[t * 4 + 3] = 0.f;
        }
    }
}

// ---------------- k13: conv1 fp32 (R2-verbatim) + conv2 popc ----------------
__global__ __launch_bounds__(256) void k13_conv12(
    const float* __restrict__ x, const float* __restrict__ sw,
    const float* __restrict__ bnp1, const uint32_t* __restrict__ wp2,
    const float* __restrict__ bnp2, uint8_t* __restrict__ fc1A) {
    const int P = 19;
    __shared__ uint32_t tile[18 * 19];
    int b = blockIdx.x, t = threadIdx.x;
    for (int i = t; i < 18 * 19; i += 256) tile[i] = 0;

    // ---- phase 1: conv1 + pool + bn1 -> packed word (round-2 verbatim) ----
    int py = t >> 4, px = t & 15;
    {
        int y0 = 2 * py - 1, x0 = 2 * px - 1;
        float in[48];
#pragma unroll
        for (int c = 0; c < 3; c++) {
            const float* xc = x + ((size_t)b * 3 + c) * 1024;
#pragma unroll
            for (int i = 0; i < 4; i++) {
                int yy = y0 + i;
                bool ry = (unsigned)yy < 32u;
#pragma unroll
                for (int j = 0; j < 4; j++) {
                    int xx = x0 + j;
                    in[c * 16 + i * 4 + j] =
                        (ry && (unsigned)xx < 32u) ? xc[yy * 32 + xx] : 0.f;
                }
            }
        }
        uint32_t word = 0;
#pragma unroll 2
        for (int o = 0; o < 32; o++) {
            const float* wo = sw + o * 32;           // uniform -> s_load
            float a00 = 0.f, a01 = 0.f, a10 = 0.f, a11 = 0.f;
#pragma unroll
            for (int c = 0; c < 3; c++)
#pragma unroll
                for (int ky = 0; ky < 3; ky++)
#pragma unroll
                    for (int kx = 0; kx < 3; kx++) {
                        float wv = wo[c * 9 + ky * 3 + kx];
                        a00 = fmaf(in[c * 16 + ky * 4 + kx], wv, a00);
                        a01 = fmaf(in[c * 16 + ky * 4 + kx + 1], wv, a01);
                        a10 = fmaf(in[c * 16 + (ky + 1) * 4 + kx], wv, a10);
                        a11 = fmaf(in[c * 16 + (ky + 1) * 4 + kx + 1], wv, a11);
                    }
            float4 p = ((const float4*)bnp1)[o];     // uniform -> s_load
            float mx = fmaxf(fmaxf(a00, a01), fmaxf(a10, a11));
            float h = __fadd_rn(mx, p.z);
            float val = __fadd_rn(__fmul_rn(h, p.x), p.y);
            word |= (val > 0.f) ? (1u << o) : 0u;
        }
        __syncthreads();                             // pad zero-fill done
        tile[(py + 1) * P + px + 1] = word;
    }
    __syncthreads();

    // ---- phase 2: conv2 popc + pool + bn2 -> +-1 bytes (R3-proven) ----
    {
        int wv = t >> 6, l = t & 63;
        int qy = l >> 3, qx = l & 7;
        uint32_t val[16];
#pragma unroll
        for (int i = 0; i < 4; i++)
#pragma unroll
            for (int j = 0; j < 4; j++)
                val[i * 4 + j] = tile[(2 * qy + i) * P + 2 * qx + j];
        bool top = (qy == 0), bot = (qy == 7), lef = (qx == 0), rig = (qx == 7);
        bool ctl = top && lef, ctr = top && rig, cbl = bot && lef, cbr = bot && rig;
#pragma unroll 2
        for (int oi = 0; oi < 16; oi++) {
            int o = wv * 16 + oi;
            const uint32_t* wo = wp2 + o * 16;       // uniform -> s_load
            uint32_t w0 = wo[0], w1 = wo[1], w2 = wo[2], w3 = wo[3], w4 = wo[4],
                     w5 = wo[5], w6 = wo[6], w7 = wo[7], w8 = wo[8];
            int t0 = 32 - 2 * __popc(w0), t1 = 32 - 2 * __popc(w1),
                t2 = 32 - 2 * __popc(w2), t3 = 32 - 2 * __popc(w3),
                t5 = 32 - 2 * __popc(w5), t6 = 32 - 2 * __popc(w6),
                t7 = 32 - 2 * __popc(w7), t8 = 32 - 2 * __popc(w8);
            int R0 = t0 + t1 + t2, R2 = t6 + t7 + t8;
            int C0 = t0 + t3 + t6, C2 = t2 + t5 + t8;
            int P00 = __popc(val[0] ^ w0) + __popc(val[1] ^ w1) + __popc(val[2] ^ w2) +
                      __popc(val[4] ^ w3) + __popc(val[5] ^ w4) + __popc(val[6] ^ w5) +
                      __popc(val[8] ^ w6) + __popc(val[9] ^ w7) + __popc(val[10] ^ w8);
            int P01 = __popc(val[1] ^ w0) + __popc(val[2] ^ w1) + __popc(val[3] ^ w2) +
                      __popc(val[5] ^ w3) + __popc(val[6] ^ w4) + __popc(val[7] ^ w5) +
                      __popc(val[9] ^ w6) + __popc(val[10] ^ w7) + __popc(val[11] ^ w8);
            int P10 = __popc(val[4] ^ w0) + __popc(val[5] ^ w1) + __popc(val[6] ^ w2) +
                      __popc(val[8] ^ w3) + __popc(val[9] ^ w4) + __popc(val[10] ^ w5) +
                      __popc(val[12] ^ w6) + __popc(val[13] ^ w7) + __popc(val[14] ^ w8);
            int P11 = __popc(val[5] ^ w0) + __popc(val[6] ^ w1) + __popc(val[7] ^ w2) +
                      __popc(val[9] ^ w3) + __popc(val[10] ^ w4) + __popc(val[11] ^ w5) +
                      __popc(val[13] ^ w6) + __popc(val[14] ^ w7) + __popc(val[15] ^ w8);
            int s00 = 288 - 2 * P00 - ((top ? R0 : 0) + (lef ? C0 : 0) - (ctl ? t0 : 0));
            int s01 = 288 - 2 * P01 - ((top ? R0 : 0) + (rig ? C2 : 0) - (ctr ? t2 : 0));
            int s10 = 288 - 2 * P10 - ((bot ? R2 : 0) + (lef ? C0 : 0) - (cbl ? t6 : 0));
            int s11 = 288 - 2 * P11 - ((bot ? R2 : 0) + (rig ? C2 : 0) - (cbr ? t8 : 0));
            int mi = max(max(s00, s01), max(s10, s11));
            float4 p = ((const float4*)bnp2)[o];     // uniform -> s_load
            float h = __fadd_rn((float)mi, p.z);
            float bv = __fadd_rn(__fmul_rn(h, p.x), p.y);
            // +-1 byte in NCHW flatten order: f = o*64 + qy*8 + qx = o*64 + l
            fc1A[(size_t)b * 4096 + o * 64 + l] = (uint8_t)(bv > 0.f ? 1 : 0xFF);
        }
    }
}

// ---------------- k4: fc1 i8 GEMM [2048,4096]x[4096,512] + bn3 ----------------
__global__ __launch_bounds__(256) void k4_fc1(
    const uint8_t* __restrict__ fc1A, const uint32_t* __restrict__ wfF1,
    const float* __restrict__ bnp3, uint8_t* __restrict__ fc2A) {
    __shared__ __align__(16) uint8_t Ab[64 * 528];
    int t = threadIdx.x;
    int mb = blockIdx.x >> 3, nb = blockIdx.x & 7;
    int l = t & 63, w = t >> 6;
    int mlane = l & 15, kq = l >> 4;
    int o = nb * 64 + w * 16 + mlane;
    int nt = nb * 4 + w;
    const vi4* wf = (const vi4*)wfF1;
    vi4 acc[4];
#pragma unroll
    for (int i = 0; i < 4; i++) acc[i] = (vi4){0, 0, 0, 0};
    int row = t >> 2, seg = t & 3;
    const uint8_t* arow = fc1A + (size_t)(mb * 64 + row) * 4096 + seg * 128;
    for (int ch = 0; ch < 8; ch++) {
        if (ch) __syncthreads();
        const uint4* src = (const uint4*)(arow + ch * 512);
        uint4* dst = (uint4*)(Ab + row * 528 + seg * 128);
#pragma unroll
        for (int i = 0; i < 8; i++) dst[i] = src[i];
        __syncthreads();
#pragma unroll
        for (int s8 = 0; s8 < 8; s8++) {
            vi4 bfr = wf[(nt * 64 + ch * 8 + s8) * 64 + l];
#pragma unroll
            for (int ms = 0; ms < 4; ms++) {
                vi4 a = *(const vi4*)(Ab + (ms * 16 + mlane) * 528 +
                                      s8 * 64 + kq * 16);
                acc[ms] = __builtin_amdgcn_mfma_i32_16x16x64_i8(a, bfr, acc[ms], 0, 0, 0);
            }
        }
    }
    float4 p = ((const float4*)bnp3)[o];
#pragma unroll
    for (int ms = 0; ms < 4; ms++)
#pragma unroll
        for (int r = 0; r < 4; r++) {
            int m = mb * 64 + ms * 16 + kq * 4 + r;
            float h = __fadd_rn((float)acc[ms][r], p.z);
            float bv = __fadd_rn(__fmul_rn(h, p.x), p.y);
            fc2A[(size_t)m * 512 + o] = (uint8_t)(bv > 0.f ? 1 : 0xFF);
        }
}

// ---------------- k56: fc2 i8 GEMM + bn4 + clip + fc3 + log_softmax ----------
// block = 16 samples; wave w covers 64 of 256 outputs; then fc3 from LDS.
__global__ __launch_bounds__(256) void k56_fc23(
    const uint8_t* __restrict__ fc2A, const uint32_t* __restrict__ wfF2,
    const float* __restrict__ bnp4, const float* __restrict__ f3w,
    const float* __restrict__ f3b, float* __restrict__ out) {
    __shared__ __align__(16) uint8_t Ab[16 * 528];
    __shared__ float hbuf[16 * 256];
    int t = threadIdx.x;
    int m0 = blockIdx.x * 16;
    int l = t & 63, w = t >> 6;
    int ml = l & 15, kq = l >> 4;
    {
        int row = t >> 4, seg = t & 15;
        const uint4* src = (const uint4*)(fc2A + (size_t)(m0 + row) * 512 + seg * 32);
        uint4* dst = (uint4*)(Ab + row * 528 + seg * 32);
        dst[0] = src[0]; dst[1] = src[1];
    }
    __syncthreads();
    const vi4* wf = (const vi4*)wfF2;
    vi4 acc[4];
#pragma unroll
    for (int i = 0; i < 4; i++) acc[i] = (vi4){0, 0, 0, 0};
#pragma unroll
    for (int s = 0; s < 8; s++) {
        vi4 a = *(const vi4*)(Ab + ml * 528 + s * 64 + kq * 16);
#pragma unroll
        for (int j = 0; j < 4; j++) {
            int nt = w * 4 + j;
            vi4 bfr = wf[(nt * 8 + s) * 64 + l];
            acc[j] = __builtin_amdgcn_mfma_i32_16x16x64_i8(a, bfr, acc[j], 0, 0, 0);
        }
    }
#pragma unroll
    for (int j = 0; j < 4; j++) {
        int o = (w * 4 + j) * 16 + ml;
        float4 p = ((const float4*)bnp4)[o];
#pragma unroll
        for (int r = 0; r < 4; r++) {
            int m = kq * 4 + r;
            float h = __fadd_rn((float)acc[j][r], p.z);
            float bv = __fadd_rn(__fmul_rn(h, p.x), p.y);
            bv = fminf(1.f, fmaxf(-1.f, bv));
            hbuf[m * 256 + o] = bv;
        }
    }
    __syncthreads();
    // fc3 + log_softmax: wave w -> samples w*4 .. w*4+3 (verbatim round-1 math)
    for (int q = 0; q < 4; q++) {
        int sm = w * 4 + q;
        float4 hv = ((const float4*)(hbuf + sm * 256))[l];
        float logits[10];
#pragma unroll
        for (int jj = 0; jj < 10; jj++) {
            float4 w4 = ((const float4*)(f3w + jj * 256))[l];
            float pp = hv.x * w4.x + hv.y * w4.y + hv.z * w4.z + hv.w * w4.w;
#pragma unroll
            for (int off = 32; off > 0; off >>= 1) pp += __shfl_xor(pp, off, 64);
            logits[jj] = pp + f3b[jj];
        }
        float mx = logits[0];
#pragma unroll
        for (int jj = 1; jj < 10; jj++) mx = fmaxf(mx, logits[jj]);
        float sum = 0.f;
#pragma unroll
        for (int jj = 0; jj < 10; jj++) sum += expf(logits[jj] - mx);
        float ls = mx + logf(sum);
        if (l < 10) out[(size_t)(m0 + sm) * 10 + l] = logits[l] - ls;
    }
}

extern "C" void kernel_launch(void* const* d_in, const int* in_sizes, int n_in,
                              void* d_out, int out_size, void* d_ws, size_t ws_size,
                              hipStream_t stream) {
    (void)in_sizes; (void)n_in; (void)out_size; (void)ws_size;
    const float* x   = (const float*)d_in[0];
    const float* c1w = (const float*)d_in[1];
    const float* c1b = (const float*)d_in[2];
    const float* b1g = (const float*)d_in[3];
    const float* b1b = (const float*)d_in[4];
    const float* b1m = (const float*)d_in[5];
    const float* b1v = (const float*)d_in[6];
    const float* c2w = (const float*)d_in[7];
    const float* c2b = (const float*)d_in[8];
    const float* b2g = (const float*)d_in[9];
    const float* b2b = (const float*)d_in[10];
    const float* b2m = (const float*)d_in[11];
    const float* b2v = (const float*)d_in[12];
    const float* f1w = (const float*)d_in[13];
    const float* f1b = (const float*)d_in[14];
    const float* b3g = (const float*)d_in[15];
    const float* b3b = (const float*)d_in[16];
    const float* b3m = (const float*)d_in[17];
    const float* b3v = (const float*)d_in[18];
    const float* f2w = (const float*)d_in[19];
    const float* f2b = (const float*)d_in[20];
    const float* b4g = (const float*)d_in[21];
    const float* b4b = (const float*)d_in[22];
    const float* b4m = (const float*)d_in[23];
    const float* b4v = (const float*)d_in[24];
    const float* f3w = (const float*)d_in[25];
    const float* f3b = (const float*)d_in[26];
    float* out = (float*)d_out;

    uint8_t* ws = (uint8_t*)d_ws;
    uint8_t*  fc1A = ws + 0;                        // [2048,4096] i8   8 MB
    uint8_t*  fc2A = ws + 8388608;                  // [2048,512]  i8   1 MB
    float*    sw1  = (float*)   (ws + 9437184);     // [32,32]
    float*    bnp1 = (float*)   (ws + 9441280);
    float*    bnp2 = (float*)   (ws + 9441792);
    float*    bnp3 = (float*)   (ws + 9442816);
    float*    bnp4 = (float*)   (ws + 9451008);
    uint32_t* wp2  = (uint32_t*)(ws + 9455104);     // [64,16] popc words
    uint32_t* wfF2 = (uint32_t*)(ws + 9459200);     // 128 KB
    uint32_t* wfF1 = (uint32_t*)(ws + 9590272);     // 2 MB

    k0_pack<<<547, 256, 0, stream>>>(c1w, c2w, f1w, f2w, c1b, c2b, f1b, f2b,
                                     b1g, b1b, b1m, b1v, b2g, b2b, b2m, b2v,
                                     b3g, b3b, b3m, b3v, b4g, b4b, b4m, b4v,
                                     sw1, wp2, wfF1, wfF2, bnp1, bnp2, bnp3, bnp4);
    k13_conv12<<<BSZ, 256, 0, stream>>>(x, sw1, bnp1, wp2, bnp2, fc1A);
    k4_fc1<<<256, 256, 0, stream>>>(fc1A, wfF1, bnp3, fc2A);
    k56_fc23<<<128, 256, 0, stream>>>(fc2A, wfF2, bnp4, f3w, f3b, out);
}